// Round 6
// baseline (338.840 us; speedup 1.0000x reference)
//
#include <hip/hip_runtime.h>
#include <math.h>

// Problem constants (from reference): cost [B, D, H, W] fp32, k=2.
constexpr int B = 16, D = 48, H = 256, W = 512;
constexpr int HW = H * W;            // 131072 = 2^17
constexpr int PIX = B * HW;          // 2,097,152 pixels
constexpr int VEC = 8;               // 8 pixels (2x float4) per thread
constexpr int NTHREADS = PIX / VEC;  // 262,144
constexpr int PF = 6;                // prefetch depth in d-slices (12 loads in flight)

typedef float f32x4 __attribute__((ext_vector_type(4)));

__device__ __forceinline__ f32x4 ldnt(const float* p) {
    return __builtin_nontemporal_load(reinterpret_cast<const f32x4*>(p));
}

// __launch_bounds__(256, 4): grid gives exactly 4 waves/SIMD (16/CU), so a
// 128-VGPR budget costs no occupancy and permits a deep load pipeline.
__global__ __launch_bounds__(256, 4) void topk2_disp_kernel(
    const float* __restrict__ cost, float* __restrict__ out) {
    const int tid = blockIdx.x * blockDim.x + threadIdx.x;   // one thread = 8 pixels
    const int p   = tid << 3;                                // pixel index
    const int b   = p >> 17;                                 // p / HW
    const int rem = p & (HW - 1);                            // p % HW

    const float* base = cost + (size_t)b * D * HW + rem;

    float v1[VEC], v2[VEC];
    int   i1[VEC], i2[VEC];
#pragma unroll
    for (int j = 0; j < VEC; ++j) {
        v1[j] = -INFINITY; v2[j] = -INFINITY; i1[j] = 0; i2[j] = 0;
    }

    // explicit register prefetch pipeline, PF slices deep.
    // Full unroll everywhere -> all pa/pb indices are compile-time constants
    // (rule #20: runtime-indexed ext_vector arrays go to scratch).
    f32x4 pa[PF], pb[PF];
#pragma unroll
    for (int s = 0; s < PF; ++s) {
        const float* row = base + (size_t)s * HW;
        pa[s] = ldnt(row);
        pb[s] = ldnt(row + 4);
    }

#pragma unroll
    for (int d = 0; d < D; ++d) {
        const int slot = d % PF;          // static after full unroll
        const f32x4 A  = pa[slot];
        const f32x4 Bv = pb[slot];
        if (d + PF < D) {                 // static predicate after unroll
            const float* row = base + (size_t)(d + PF) * HW;
            pa[slot] = ldnt(row);
            pb[slot] = ldnt(row + 4);
        }
        float x[VEC] = {A.x, A.y, A.z, A.w, Bv.x, Bv.y, Bv.z, Bv.w};
#pragma unroll
        for (int j = 0; j < VEC; ++j) {
            // strict > : ties keep the earlier (lower) index, matching lax.top_k
            const bool g1 = x[j] > v1[j];
            const bool g2 = x[j] > v2[j];
            // v2' = middle of {x, v1, v2} (v1 >= v2)  -> v_med3-able
            v2[j] = g1 ? v1[j] : (g2 ? x[j] : v2[j]);
            i2[j] = g1 ? i1[j] : (g2 ? d    : i2[j]);
            v1[j] = g1 ? x[j]  : v1[j];
            i1[j] = g1 ? d     : i1[j];
        }
    }

    float res[VEC];
#pragma unroll
    for (int j = 0; j < VEC; ++j) {
        // softmax over [v1, v2], v1 >= v2: e = exp(v2-v1)
        const float e   = expf(v2[j] - v1[j]);
        const float inv = 1.0f / (1.0f + e);
        res[j] = ((float)i1[j] + e * (float)i2[j]) * inv;
    }
    f32x4 o0 = {res[0], res[1], res[2], res[3]};
    f32x4 o1 = {res[4], res[5], res[6], res[7]};
    __builtin_nontemporal_store(o0, reinterpret_cast<f32x4*>(out + p));
    __builtin_nontemporal_store(o1, reinterpret_cast<f32x4*>(out + p + 4));
}

extern "C" void kernel_launch(void* const* d_in, const int* in_sizes, int n_in,
                              void* d_out, int out_size, void* d_ws, size_t ws_size,
                              hipStream_t stream) {
    const float* cost = (const float*)d_in[0];
    // d_in[1] is k (always 2 for this problem; hard-coded top-2 path)
    float* out = (float*)d_out;

    constexpr int BLOCK = 256;
    constexpr int GRID  = NTHREADS / BLOCK;  // 1024
    topk2_disp_kernel<<<GRID, BLOCK, 0, stream>>>(cost, out);
}

// Round 7
// 82.102 us; speedup vs baseline: 4.1271x; 4.1271x over previous
//
#include <hip/hip_runtime.h>
#include <math.h>

// Problem constants (from reference): cost [B, D, H, W] fp32, k=2.
constexpr int B = 16, D = 48, H = 256, W = 512;
constexpr int HW = H * W;            // 131072 = 2^17
constexpr int PIX = B * HW;          // 2,097,152 pixels
constexpr int VEC = 8;               // 8 pixels per thread (2 chunks of 4)
constexpr int BLOCK = 256;           // 4 waves
constexpr int PXB = BLOCK * VEC;     // 2048 pixels per block
constexpr int GRID = PIX / PXB;      // 1024 blocks

typedef float f32x4 __attribute__((ext_vector_type(4)));

__device__ __forceinline__ f32x4 ldnt(const float* p) {
    return __builtin_nontemporal_load(reinterpret_cast<const f32x4*>(p));
}

__global__ __launch_bounds__(BLOCK) void topk2_disp_kernel(
    const float* __restrict__ cost, float* __restrict__ out) {
    const int t = threadIdx.x;
    const int w = t >> 6;                       // wave 0..3
    const int l = t & 63;                       // lane
    // wave's base pixel; PXB divides HW so a block never crosses b.
    const int pw  = blockIdx.x * PXB + w * 512;
    const int b   = pw >> 17;                   // pw / HW
    const int rem = pw & (HW - 1);

    // CHUNKED layout: lane l owns px [pw + l*4, +4) (chunk A) and
    // [pw + 256 + l*4, +4) (chunk B). Each load instruction is a fully
    // coalesced, contiguous 1 KiB wave-read — no intra-instruction stride,
    // so NT eviction cannot cause over-fetch.
    const float* gw = cost + (size_t)b * D * HW + rem;  // wave base, slice 0
    const int la = l * 4;            // chunk A lane offset (floats)
    const int lb = 256 + l * 4;      // chunk B lane offset

    float v1[VEC], v2[VEC];
    int   i1[VEC], i2[VEC];
#pragma unroll
    for (int j = 0; j < VEC; ++j) {
        v1[j] = -INFINITY; v2[j] = -INFINITY; i1[j] = 0; i2[j] = 0;
    }

#pragma unroll
    for (int d = 0; d < D; ++d) {
        const float* row = gw + (size_t)d * HW;
        const f32x4 A  = ldnt(row + la);
        const f32x4 Bv = ldnt(row + lb);
        float x[VEC] = {A.x, A.y, A.z, A.w, Bv.x, Bv.y, Bv.z, Bv.w};
#pragma unroll
        for (int j = 0; j < VEC; ++j) {
            // strict > : ties keep the earlier (lower) index, matching lax.top_k
            if (x[j] > v1[j]) {
                v2[j] = v1[j]; i2[j] = i1[j];
                v1[j] = x[j];  i1[j] = d;
            } else if (x[j] > v2[j]) {
                v2[j] = x[j];  i2[j] = d;
            }
        }
    }

    float res[VEC];
#pragma unroll
    for (int j = 0; j < VEC; ++j) {
        // softmax over [v1, v2], v1 >= v2: e = exp(v2-v1)
        const float e   = expf(v2[j] - v1[j]);
        const float inv = 1.0f / (1.0f + e);
        res[j] = ((float)i1[j] + e * (float)i2[j]) * inv;
    }
    f32x4 oA = {res[0], res[1], res[2], res[3]};
    f32x4 oB = {res[4], res[5], res[6], res[7]};
    float* ow = out + pw;
    __builtin_nontemporal_store(oA, reinterpret_cast<f32x4*>(ow + la));
    __builtin_nontemporal_store(oB, reinterpret_cast<f32x4*>(ow + lb));
}

extern "C" void kernel_launch(void* const* d_in, const int* in_sizes, int n_in,
                              void* d_out, int out_size, void* d_ws, size_t ws_size,
                              hipStream_t stream) {
    const float* cost = (const float*)d_in[0];
    // d_in[1] is k (always 2 for this problem; hard-coded top-2 path)
    float* out = (float*)d_out;
    topk2_disp_kernel<<<GRID, BLOCK, 0, stream>>>(cost, out);
}